// Round 12
// baseline (339.339 us; speedup 1.0000x reference)
//
#include <hip/hip_runtime.h>
#include <hip/hip_bf16.h>

typedef unsigned short ushort_t;
typedef __attribute__((ext_vector_type(8))) short short8;
typedef __attribute__((ext_vector_type(4))) float f32x4;

#define HIDDEN 256
#define N_NODES 50000

__device__ __forceinline__ unsigned int f2bf(float f) {
    union { float f; unsigned int i; } v; v.f = f;
    return (v.i + 0x7fffu + ((v.i >> 16) & 1u)) >> 16;
}
__device__ __forceinline__ float bf2f(unsigned int u) {
    union { unsigned int i; float f; } v; v.i = u << 16; return v.f;
}

// ws layout (bytes)
#define OFF_MVB    0u                         // 50000*128 u32 = 25,600,000
#define OFF_WF     25600000u                  // 65536 bf16 fragment-major
#define OFF_CNT    25731072u                  // int[50000]
#define OFF_OFFS   25931072u                  // int[50001]
#define OFF_CUR    26131076u                  // int[50000]
#define OFF_ELIST  26331076u                  // int[300000]
#define OFF_BSUM   27531076u                  // int[256]

#define SCAN_NBLK ((N_NODES + 255) / 256)     // 196

// Kernel 0: pack W fp32 -> bf16 fragment-major.
// Wf[((g*8 + kk)*64 + lane)*8 + t] = W[g*16 + (lane&15)][kk*32 + (lane>>4)*8 + t]
__global__ void convert_w_frag(const float* __restrict__ W, ushort_t* __restrict__ Wf, int n) {
    int i = blockIdx.x * blockDim.x + threadIdx.x;
    if (i >= n) return;
    const int t    = i & 7;
    const int lane = (i >> 3) & 63;
    const int kk   = (i >> 9) & 7;
    const int g    = i >> 12;
    const int j = g * 16 + (lane & 15);
    const int k = kk * 32 + ((lane >> 4) & 3) * 8 + t;
    Wf[i] = (ushort_t)f2bf(W[j * HIDDEN + k]);
}

// zero int buffer (graph-safe)
__global__ void zero_i32(int* __restrict__ p, int n) {
    int i = blockIdx.x * blockDim.x + threadIdx.x;
    if (i < n) p[i] = 0;
}

// histogram of dst
__global__ void count_dst(const int* __restrict__ dst, int* __restrict__ cnt, int n) {
    int i = blockIdx.x * blockDim.x + threadIdx.x;
    if (i < n) atomicAdd(&cnt[dst[i]], 1);
}

// per-256-block exclusive scan, block sums out
__global__ __launch_bounds__(256)
void block_scan(const int* __restrict__ cnt, int* __restrict__ offs,
                int* __restrict__ bsum) {
    __shared__ int sh[256];
    const int t = threadIdx.x;
    const int idx = blockIdx.x * 256 + t;
    int v = (idx < N_NODES) ? cnt[idx] : 0;
    sh[t] = v;
    __syncthreads();
    for (int off = 1; off < 256; off <<= 1) {
        int x = (t >= off) ? sh[t - off] : 0;
        __syncthreads();
        sh[t] += x;
        __syncthreads();
    }
    if (idx < N_NODES) offs[idx] = sh[t] - v;
    if (t == 255) bsum[blockIdx.x] = sh[255];
}

// exclusive scan of block sums (single block, nb <= 256)
__global__ __launch_bounds__(256)
void scan_bsum(int* __restrict__ bsum, int nb) {
    __shared__ int sh[256];
    const int t = threadIdx.x;
    int v = (t < nb) ? bsum[t] : 0;
    sh[t] = v;
    __syncthreads();
    for (int off = 1; off < 256; off <<= 1) {
        int x = (t >= off) ? sh[t - off] : 0;
        __syncthreads();
        sh[t] += x;
        __syncthreads();
    }
    if (t < nb) bsum[t] = sh[t] - v;
}

// offs += base; cur = offs; offs[N] = n_edges
__global__ __launch_bounds__(256)
void add_base(int* __restrict__ offs, const int* __restrict__ bsum,
              int* __restrict__ cur, int n_edges) {
    const int idx = blockIdx.x * 256 + threadIdx.x;
    if (idx < N_NODES) {
        int o = offs[idx] + bsum[idx >> 8];
        offs[idx] = o;
        cur[idx] = o;
    }
    if (idx == 0) offs[N_NODES] = n_edges;
}

// bucket edge ids by destination
__global__ void fill_elist(const int* __restrict__ dst, int* __restrict__ cur,
                           int* __restrict__ elist, int n) {
    int i = blockIdx.x * blockDim.x + threadIdx.x;
    if (i < n) {
        int d = dst[i];
        int pos = atomicAdd(&cur[d], 1);
        elist[pos] = i;
    }
}

// Kernel 4: per-(node, col-half) relu-sum -> Mvb (bf16)
__global__ __launch_bounds__(256)
void node_gather_sum(const float* __restrict__ E,
                     const int* __restrict__ offs,
                     const int* __restrict__ elist,
                     unsigned int* __restrict__ Mvb) {
    const int w    = blockIdx.x * 4 + (threadIdx.x >> 6);
    const int node = w >> 1;
    const int half = w & 1;
    const int lane = threadIdx.x & 63;
    if (node >= N_NODES) return;
    const float* Eh = E + half * 128 + lane * 2;
    const int s0 = offs[node];
    const int s1 = offs[node + 1];
    float ax = 0.f, ay = 0.f;
    int j = s0;
    for (; j + 4 <= s1; j += 4) {
        const int e0 = elist[j], e1 = elist[j + 1], e2 = elist[j + 2], e3 = elist[j + 3];
        float2 v0 = *(const float2*)(Eh + (size_t)e0 * HIDDEN);
        float2 v1 = *(const float2*)(Eh + (size_t)e1 * HIDDEN);
        float2 v2 = *(const float2*)(Eh + (size_t)e2 * HIDDEN);
        float2 v3 = *(const float2*)(Eh + (size_t)e3 * HIDDEN);
        ax += fmaxf(v0.x, 0.f) + fmaxf(v1.x, 0.f) + fmaxf(v2.x, 0.f) + fmaxf(v3.x, 0.f);
        ay += fmaxf(v0.y, 0.f) + fmaxf(v1.y, 0.f) + fmaxf(v2.y, 0.f) + fmaxf(v3.y, 0.f);
    }
    for (; j < s1; ++j) {
        float2 v = *(const float2*)(Eh + (size_t)elist[j] * HIDDEN);
        ax += fmaxf(v.x, 0.f);
        ay += fmaxf(v.y, 0.f);
    }
    Mvb[(size_t)node * 128 + half * 64 + lane] = f2bf(ax) | (f2bf(ay) << 16);
}

// Kernel 5: out = (Mv[src] - relu(E[rev])) @ W.T + b
// BARRIER-FREE: each wave owns 16 rows end-to-end in its private 8KB LDS
// quadrant. Stage (coalesced 1KB E / 512B Mv per row) -> MFMA with W-frags
// from L2-resident Wf -> float4 epilogue. No __syncthreads anywhere; waves
// overlap each other's staging stalls.
__global__ __launch_bounds__(256, 4)
void gemm_wave(const float* __restrict__ E,
               const int* __restrict__ src,
               const int* __restrict__ rev,
               const unsigned int* __restrict__ Mvb,
               const ushort_t* __restrict__ Wf,
               const float* __restrict__ bias,
               float* __restrict__ out, int n_edges) {
    __shared__ __align__(16) unsigned char lds[4 * 16 * 512];   // 8KB per wave
    const int tid  = threadIdx.x;
    const int lane = tid & 63;
    const int wid  = tid >> 6;
    const int l15  = lane & 15;
    const int hi16 = lane >> 4;
    const int row0 = (blockIdx.x * 4 + wid) * 16;
    if (row0 >= n_edges) return;
    unsigned char* mylds = lds + wid * 8192;

    // ---- stage 16 rows, 2 batches of 8 (16 independent loads in flight)
#pragma unroll
    for (int b = 0; b < 2; ++b) {
        float4 ev[8];
        uint2  mv[8];
#pragma unroll
        for (int i = 0; i < 8; ++i) {
            int gr = row0 + b * 8 + i;
            int grc = (gr < n_edges) ? gr : (n_edges - 1);
            ev[i] = *(const float4*)(E + (size_t)rev[grc] * HIDDEN + lane * 4);
            mv[i] = *(const uint2*)(Mvb + (size_t)src[grc] * 128 + lane * 2);
        }
#pragma unroll
        for (int i = 0; i < 8; ++i) {
            const int r = b * 8 + i;
            uint2 o;
            o.x = f2bf(bf2f(mv[i].x & 0xffffu) - fmaxf(ev[i].x, 0.f)) |
                  (f2bf(bf2f(mv[i].x >> 16)    - fmaxf(ev[i].y, 0.f)) << 16);
            o.y = f2bf(bf2f(mv[i].y & 0xffffu) - fmaxf(ev[i].z, 0.f)) |
                  (f2bf(bf2f(mv[i].y >> 16)    - fmaxf(ev[i].w, 0.f)) << 16);
            const int slot = (lane >> 1) ^ (r & 7);
            *(uint2*)(mylds + r * 512 + slot * 16 + (lane & 1) * 8) = o;
        }
    }
    // (no barrier: hardware lgkmcnt orders this wave's ds_write -> ds_read)

    // ---- MFMA: 16 rows x 256 cols, 8 kk steps x 16 col-groups
    f32x4 acc[16];
#pragma unroll
    for (int n = 0; n < 16; ++n)
        acc[n] = (f32x4){0.f, 0.f, 0.f, 0.f};

    const int r7l = l15 & 7;
#pragma unroll 1
    for (int kk = 0; kk < 8; ++kk) {
        const int slotbyte = ((kk * 4 + hi16) ^ r7l) * 16;
        short8 a = *(const short8*)(mylds + l15 * 512 + slotbyte);
#pragma unroll
        for (int n = 0; n < 16; ++n) {
            short8 bfr = *(const short8*)(Wf + (size_t)(((n * 8 + kk) * 64 + lane) << 3));
            acc[n] = __builtin_amdgcn_mfma_f32_16x16x32_bf16(bfr, a, acc[n], 0, 0, 0);
        }
    }

    // ---- epilogue: lane's row = row0 + l15; cols n*16 + hi16*4 .. +3
    const int row = row0 + l15;
    if (row < n_edges) {
        float* orow = out + (size_t)row * HIDDEN;
#pragma unroll
        for (int n = 0; n < 16; ++n) {
            const int cb = n * 16 + hi16 * 4;
            float4 bv = *(const float4*)(bias + cb);
            float4 o;
            o.x = acc[n][0] + bv.x;
            o.y = acc[n][1] + bv.y;
            o.z = acc[n][2] + bv.z;
            o.w = acc[n][3] + bv.w;
            *(float4*)(orow + cb) = o;
        }
    }
}

extern "C" void kernel_launch(void* const* d_in, const int* in_sizes, int n_in,
                              void* d_out, int out_size, void* d_ws, size_t ws_size,
                              hipStream_t stream) {
    const float* E    = (const float*)d_in[0];
    const int*   ei   = (const int*)d_in[1];
    const int*   rev  = (const int*)d_in[2];
    const float* W    = (const float*)d_in[3];
    const float* bias = (const float*)d_in[4];
    float* out = (float*)d_out;
    const int n_edges = in_sizes[2];
    const int* srcI = ei;              // edge_index[0]
    const int* dstI = ei + n_edges;    // edge_index[1]

    char* ws = (char*)d_ws;
    unsigned int* Mvb  = (unsigned int*)(ws + OFF_MVB);
    ushort_t*     Wf   = (ushort_t*)(ws + OFF_WF);
    int*          cnt  = (int*)(ws + OFF_CNT);
    int*          offs = (int*)(ws + OFF_OFFS);
    int*          cur  = (int*)(ws + OFF_CUR);
    int*          elst = (int*)(ws + OFF_ELIST);
    int*          bsum = (int*)(ws + OFF_BSUM);

    zero_i32<<<SCAN_NBLK, 256, 0, stream>>>(cnt, N_NODES);
    convert_w_frag<<<(HIDDEN * HIDDEN + 255) / 256, 256, 0, stream>>>(W, Wf, HIDDEN * HIDDEN);

    count_dst<<<(n_edges + 255) / 256, 256, 0, stream>>>(dstI, cnt, n_edges);
    block_scan<<<SCAN_NBLK, 256, 0, stream>>>(cnt, offs, bsum);
    scan_bsum<<<1, 256, 0, stream>>>(bsum, SCAN_NBLK);
    add_base<<<SCAN_NBLK, 256, 0, stream>>>(offs, bsum, cur, n_edges);
    fill_elist<<<(n_edges + 255) / 256, 256, 0, stream>>>(dstI, cur, elst, n_edges);

    const int nwaves = N_NODES * 2;
    node_gather_sum<<<(nwaves + 3) / 4, 256, 0, stream>>>(E, offs, elst, Mvb);

    const int ntiles = (n_edges + 15) / 16;
    const int nblk = (ntiles + 3) / 4;
    gemm_wave<<<nblk, 256, 0, stream>>>(E, srcI, rev, Mvb, Wf, bias, out, n_edges);
}

// Round 13
// 329.993 us; speedup vs baseline: 1.0283x; 1.0283x over previous
//
#include <hip/hip_runtime.h>
#include <hip/hip_bf16.h>

typedef unsigned short ushort_t;
typedef __attribute__((ext_vector_type(8))) short short8;
typedef __attribute__((ext_vector_type(4))) float f32x4;

#define HIDDEN 256
#define N_NODES 50000
#define BM 64

__device__ __forceinline__ unsigned int f2bf(float f) {
    union { float f; unsigned int i; } v; v.f = f;
    return (v.i + 0x7fffu + ((v.i >> 16) & 1u)) >> 16;
}
__device__ __forceinline__ float bf2f(unsigned int u) {
    union { unsigned int i; float f; } v; v.i = u << 16; return v.f;
}

// ws layout (bytes)
#define OFF_P      0u                         // 300000*128 u32 (bf16x2) = 153,600,000
#define OFF_Q      153600000u                 // 50000*256 f32 = 51,200,000
#define OFF_WF     204800000u                 // 65536 bf16 fragment-major
#define OFF_CNT    204931072u                 // int[50000]
#define OFF_OFFS   205131072u                 // int[50001]
#define OFF_CUR    205331076u                 // int[50000]
#define OFF_ELIST  205531076u                 // int[300000]
#define OFF_BSUM   206731076u                 // int[256]

#define SCAN_NBLK ((N_NODES + 255) / 256)     // 196

// Kernel 0: zero cnt + pack W fp32 -> bf16 fragment-major (merged).
// Wf[((g*8 + kk)*64 + lane)*8 + t] = W[g*16 + (lane&15)][kk*32 + (lane>>4)*8 + t]
__global__ void prep(const float* __restrict__ W, ushort_t* __restrict__ Wf,
                     int* __restrict__ cnt) {
    int i = blockIdx.x * blockDim.x + threadIdx.x;
    if (i < N_NODES) cnt[i] = 0;
    if (i < HIDDEN * HIDDEN) {
        const int t    = i & 7;
        const int lane = (i >> 3) & 63;
        const int kk   = (i >> 9) & 7;
        const int g    = i >> 12;
        const int j = g * 16 + (lane & 15);
        const int k = kk * 32 + ((lane >> 4) & 3) * 8 + t;
        Wf[i] = (ushort_t)f2bf(W[j * HIDDEN + k]);
    }
}

// histogram of dst
__global__ void count_dst(const int* __restrict__ dst, int* __restrict__ cnt, int n) {
    int i = blockIdx.x * blockDim.x + threadIdx.x;
    if (i < n) atomicAdd(&cnt[dst[i]], 1);
}

// per-256-block exclusive scan, block sums out
__global__ __launch_bounds__(256)
void block_scan(const int* __restrict__ cnt, int* __restrict__ offs,
                int* __restrict__ bsum) {
    __shared__ int sh[256];
    const int t = threadIdx.x;
    const int idx = blockIdx.x * 256 + t;
    int v = (idx < N_NODES) ? cnt[idx] : 0;
    sh[t] = v;
    __syncthreads();
    for (int off = 1; off < 256; off <<= 1) {
        int x = (t >= off) ? sh[t - off] : 0;
        __syncthreads();
        sh[t] += x;
        __syncthreads();
    }
    if (idx < N_NODES) offs[idx] = sh[t] - v;
    if (t == 255) bsum[blockIdx.x] = sh[255];
}

// exclusive scan of block sums (single block, nb <= 256)
__global__ __launch_bounds__(256)
void scan_bsum(int* __restrict__ bsum, int nb) {
    __shared__ int sh[256];
    const int t = threadIdx.x;
    int v = (t < nb) ? bsum[t] : 0;
    sh[t] = v;
    __syncthreads();
    for (int off = 1; off < 256; off <<= 1) {
        int x = (t >= off) ? sh[t - off] : 0;
        __syncthreads();
        sh[t] += x;
        __syncthreads();
    }
    if (t < nb) bsum[t] = sh[t] - v;
}

// offs += base; cur = offs; offs[N] = n_edges
__global__ __launch_bounds__(256)
void add_base(int* __restrict__ offs, const int* __restrict__ bsum,
              int* __restrict__ cur, int n_edges) {
    const int idx = blockIdx.x * 256 + threadIdx.x;
    if (idx < N_NODES) {
        int o = offs[idx] + bsum[idx >> 8];
        offs[idx] = o;
        cur[idx] = o;
    }
    if (idx == 0) offs[N_NODES] = n_edges;
}

// bucket edge ids by destination
__global__ void fill_elist(const int* __restrict__ dst, int* __restrict__ cur,
                           int* __restrict__ elist, int n) {
    int i = blockIdx.x * blockDim.x + threadIdx.x;
    if (i < n) {
        int d = dst[i];
        int pos = atomicAdd(&cur[d], 1);
        elist[pos] = i;
    }
}

// Kernel P: P[e] = bf16( relu(E[e]) @ W.T ).  DENSE sequential rows -- the
// only kernel that reads E. Round-8 GEMM structure (wave-per-row staging,
// XOR-swizzled LDS, swapped MFMA operands), minus all gather.
__global__ __launch_bounds__(256, 3)
void gemm_P(const float* __restrict__ E,
            const ushort_t* __restrict__ Wf,
            unsigned int* __restrict__ P, int n_edges) {
    __shared__ __align__(16) unsigned char lds[BM * 512];
    const int tid = threadIdx.x;
    const int row0 = blockIdx.x * BM;
    const int lane = tid & 63;
    const int wid  = tid >> 6;

    // ---- stage: 16 sequential rows per wave, relu+bf16, swizzled slots
    {
        const int wrow = wid * 16;
#pragma unroll
        for (int b = 0; b < 2; ++b) {
            float4 ev[8];
#pragma unroll
            for (int i = 0; i < 8; ++i) {
                int gr = row0 + wrow + b * 8 + i;
                int grc = (gr < n_edges) ? gr : (n_edges - 1);
                ev[i] = *(const float4*)(E + (size_t)grc * HIDDEN + lane * 4);
            }
#pragma unroll
            for (int i = 0; i < 8; ++i) {
                const int r = wrow + b * 8 + i;
                uint2 o;
                o.x = f2bf(fmaxf(ev[i].x, 0.f)) | (f2bf(fmaxf(ev[i].y, 0.f)) << 16);
                o.y = f2bf(fmaxf(ev[i].z, 0.f)) | (f2bf(fmaxf(ev[i].w, 0.f)) << 16);
                const int slot = (lane >> 1) ^ (r & 7);
                *(uint2*)(lds + r * 512 + slot * 16 + (lane & 1) * 8) = o;
            }
        }
    }
    __syncthreads();

    const int l15   = lane & 15;
    const int hi16  = lane >> 4;
    const int wcol0 = wid * 64;
    const int r7l   = l15 & 7;

    f32x4 acc[4][4];
#pragma unroll
    for (int m = 0; m < 4; ++m)
#pragma unroll
        for (int n = 0; n < 4; ++n)
            acc[m][n] = (f32x4){0.f, 0.f, 0.f, 0.f};

#pragma unroll 2
    for (int kk = 0; kk < 8; ++kk) {
        const int slotbyte = ((kk * 4 + hi16) ^ r7l) * 16;
        short8 a[4], bfr[4];
#pragma unroll
        for (int m = 0; m < 4; ++m)
            a[m] = *(const short8*)(lds + (m * 16 + l15) * 512 + slotbyte);
#pragma unroll
        for (int n = 0; n < 4; ++n)
            bfr[n] = *(const short8*)(Wf + (size_t)((((wid * 4 + n) * 8 + kk) * 64 + lane) << 3));
#pragma unroll
        for (int m = 0; m < 4; ++m)
#pragma unroll
            for (int n = 0; n < 4; ++n)
                acc[m][n] = __builtin_amdgcn_mfma_f32_16x16x32_bf16(bfr[n], a[m], acc[m][n], 0, 0, 0);
    }

    // ---- epilogue: store P bf16 (no bias here). lane: row l15+16m, 4 cols.
#pragma unroll
    for (int m = 0; m < 4; ++m) {
        const int row = row0 + m * 16 + l15;
        if (row < n_edges) {
            unsigned int* prow = P + (size_t)row * (HIDDEN / 2);
#pragma unroll
            for (int n = 0; n < 4; ++n) {
                const int cb = wcol0 + n * 16 + hi16 * 4;
                uint2 o;
                o.x = f2bf(acc[m][n][0]) | (f2bf(acc[m][n][1]) << 16);
                o.y = f2bf(acc[m][n][2]) | (f2bf(acc[m][n][3]) << 16);
                *(uint2*)(prow + (cb >> 1)) = o;
            }
        }
    }
}

// Kernel Q: Q[v] = sum_{e: dst[e]=v} P[e]   (fp32 out; P is L3-hot).
// Wave per node, lane owns 4 cols (uint2 per row), 4-deep unroll.
__global__ __launch_bounds__(256)
void q_gather(const unsigned int* __restrict__ P,
              const int* __restrict__ offs,
              const int* __restrict__ elist,
              float* __restrict__ Q) {
    const int node = blockIdx.x * 4 + (threadIdx.x >> 6);
    const int lane = threadIdx.x & 63;
    if (node >= N_NODES) return;
    const int d0 = offs[node];
    const int d1 = offs[node + 1];
    float q0 = 0.f, q1 = 0.f, q2 = 0.f, q3 = 0.f;
    int j = d0;
    for (; j + 4 <= d1; j += 4) {
        const int e0 = elist[j], e1 = elist[j + 1], e2 = elist[j + 2], e3 = elist[j + 3];
        uint2 p0 = *(const uint2*)(P + (size_t)e0 * 128 + lane * 2);
        uint2 p1 = *(const uint2*)(P + (size_t)e1 * 128 + lane * 2);
        uint2 p2 = *(const uint2*)(P + (size_t)e2 * 128 + lane * 2);
        uint2 p3 = *(const uint2*)(P + (size_t)e3 * 128 + lane * 2);
        q0 += bf2f(p0.x & 0xffffu) + bf2f(p1.x & 0xffffu) + bf2f(p2.x & 0xffffu) + bf2f(p3.x & 0xffffu);
        q1 += bf2f(p0.x >> 16)     + bf2f(p1.x >> 16)     + bf2f(p2.x >> 16)     + bf2f(p3.x >> 16);
        q2 += bf2f(p0.y & 0xffffu) + bf2f(p1.y & 0xffffu) + bf2f(p2.y & 0xffffu) + bf2f(p3.y & 0xffffu);
        q3 += bf2f(p0.y >> 16)     + bf2f(p1.y >> 16)     + bf2f(p2.y >> 16)     + bf2f(p3.y >> 16);
    }
    for (; j < d1; ++j) {
        uint2 p = *(const uint2*)(P + (size_t)elist[j] * 128 + lane * 2);
        q0 += bf2f(p.x & 0xffffu);
        q1 += bf2f(p.x >> 16);
        q2 += bf2f(p.y & 0xffffu);
        q3 += bf2f(p.y >> 16);
    }
    float4 o = {q0, q1, q2, q3};
    *(float4*)(Q + (size_t)node * HIDDEN + lane * 4) = o;
}

// Kernel emit: out[e] = Q[src[e]] - P[rev[e]] + b.  Edge-parallel, wave per
// 4 edges; per edge: 1KB Q row + 512B P row loads (8 in flight), 1KB store.
__global__ __launch_bounds__(256)
void emit(const float* __restrict__ Q,
          const unsigned int* __restrict__ P,
          const int* __restrict__ src,
          const int* __restrict__ rev,
          const float* __restrict__ bias,
          float* __restrict__ out, int n_edges) {
    const int wave = blockIdx.x * 4 + (threadIdx.x >> 6);
    const int lane = threadIdx.x & 63;
    const int e0 = wave * 4;
    if (e0 >= n_edges) return;
    const int nr = (n_edges - e0 < 4) ? (n_edges - e0) : 4;

    float4 qv[4];
    uint2  pv[4];
#pragma unroll
    for (int i = 0; i < 4; ++i) {
        int e = e0 + ((i < nr) ? i : 0);
        qv[i] = *(const float4*)(Q + (size_t)src[e] * HIDDEN + lane * 4);
        pv[i] = *(const uint2*)(P + (size_t)rev[e] * 128 + lane * 2);
    }
    float4 bv = *(const float4*)(bias + lane * 4);
#pragma unroll
    for (int i = 0; i < 4; ++i) {
        if (i < nr) {
            float4 o;
            o.x = qv[i].x - bf2f(pv[i].x & 0xffffu) + bv.x;
            o.y = qv[i].y - bf2f(pv[i].x >> 16)     + bv.y;
            o.z = qv[i].z - bf2f(pv[i].y & 0xffffu) + bv.z;
            o.w = qv[i].w - bf2f(pv[i].y >> 16)     + bv.w;
            *(float4*)(out + (size_t)(e0 + i) * HIDDEN + lane * 4) = o;
        }
    }
}

extern "C" void kernel_launch(void* const* d_in, const int* in_sizes, int n_in,
                              void* d_out, int out_size, void* d_ws, size_t ws_size,
                              hipStream_t stream) {
    const float* E    = (const float*)d_in[0];
    const int*   ei   = (const int*)d_in[1];
    const int*   rev  = (const int*)d_in[2];
    const float* W    = (const float*)d_in[3];
    const float* bias = (const float*)d_in[4];
    float* out = (float*)d_out;
    const int n_edges = in_sizes[2];
    const int* srcI = ei;              // edge_index[0]
    const int* dstI = ei + n_edges;    // edge_index[1]

    char* ws = (char*)d_ws;
    unsigned int* P    = (unsigned int*)(ws + OFF_P);
    float*        Q    = (float*)(ws + OFF_Q);
    ushort_t*     Wf   = (ushort_t*)(ws + OFF_WF);
    int*          cnt  = (int*)(ws + OFF_CNT);
    int*          offs = (int*)(ws + OFF_OFFS);
    int*          cur  = (int*)(ws + OFF_CUR);
    int*          elst = (int*)(ws + OFF_ELIST);
    int*          bsum = (int*)(ws + OFF_BSUM);

    prep<<<(HIDDEN * HIDDEN + 255) / 256, 256, 0, stream>>>(W, Wf, cnt);

    count_dst<<<(n_edges + 255) / 256, 256, 0, stream>>>(dstI, cnt, n_edges);
    block_scan<<<SCAN_NBLK, 256, 0, stream>>>(cnt, offs, bsum);
    scan_bsum<<<1, 256, 0, stream>>>(bsum, SCAN_NBLK);
    add_base<<<SCAN_NBLK, 256, 0, stream>>>(offs, bsum, cur, n_edges);
    fill_elist<<<(n_edges + 255) / 256, 256, 0, stream>>>(dstI, cur, elst, n_edges);

    const int nblk = (n_edges + BM - 1) / BM;
    gemm_P<<<nblk, 256, 0, stream>>>(E, Wf, P, n_edges);

    q_gather<<<(N_NODES + 3) / 4, 256, 0, stream>>>(P, offs, elst, Q);

    const int nwave = (n_edges + 3) / 4;
    emit<<<(nwave + 3) / 4, 256, 0, stream>>>(Q, P, srcI, rev, bias, out, n_edges);
}

// Round 15
// 272.346 us; speedup vs baseline: 1.2460x; 1.2117x over previous
//
#include <hip/hip_runtime.h>
#include <hip/hip_bf16.h>

typedef unsigned short ushort_t;
typedef __attribute__((ext_vector_type(8))) short short8;
typedef __attribute__((ext_vector_type(4))) float f32x4;
typedef __attribute__((ext_vector_type(2))) float f32x2;

#define HIDDEN 256
#define N_NODES 50000
#define BM 64
#define LDSROW 512   // bf16 row = 512B; XOR-swizzled 16B slots

__device__ __forceinline__ unsigned int f2bf(float f) {
    union { float f; unsigned int i; } v; v.f = f;
    return (v.i + 0x7fffu + ((v.i >> 16) & 1u)) >> 16;
}
__device__ __forceinline__ float bf2f(unsigned int u) {
    union { unsigned int i; float f; } v; v.i = u << 16; return v.f;
}

// ws layout (bytes)
#define OFF_MVB    0u                         // 50000*128 u32 = 25,600,000
#define OFF_WF     25600000u                  // 65536 bf16 fragment-major
#define OFF_CNT    25731072u                  // int[50000]
#define OFF_OFFS   25931072u                  // int[50001]
#define OFF_CUR    26131076u                  // int[50000]
#define OFF_ELIST  26331076u                  // int[300000]
#define OFF_BSUM   27531076u                  // int[256]

#define SCAN_NBLK ((N_NODES + 255) / 256)     // 196

// Kernel 0: pack W fp32 -> bf16 fragment-major.
// Wf[(((g*8)+kk)*64 + lane)*8 + t] = W[g*16 + (lane&15)][kk*32 + (lane>>4)*8 + t]
__global__ void convert_w_frag(const float* __restrict__ W, ushort_t* __restrict__ Wf, int n) {
    int i = blockIdx.x * blockDim.x + threadIdx.x;
    if (i >= n) return;
    const int t    = i & 7;
    const int lane = (i >> 3) & 63;
    const int kk   = (i >> 9) & 7;
    const int g    = i >> 12;
    const int j = g * 16 + (lane & 15);
    const int k = kk * 32 + ((lane >> 4) & 3) * 8 + t;
    Wf[i] = (ushort_t)f2bf(W[j * HIDDEN + k]);
}

// zero int buffer (graph-safe, no fillBuffer artifact)
__global__ void zero_i32(int* __restrict__ p, int n) {
    int i = blockIdx.x * blockDim.x + threadIdx.x;
    if (i < n) p[i] = 0;
}

// histogram of dst
__global__ void count_dst(const int* __restrict__ dst, int* __restrict__ cnt, int n) {
    int i = blockIdx.x * blockDim.x + threadIdx.x;
    if (i < n) atomicAdd(&cnt[dst[i]], 1);
}

// per-256-block exclusive scan, block sums out
__global__ __launch_bounds__(256)
void block_scan(const int* __restrict__ cnt, int* __restrict__ offs,
                int* __restrict__ bsum) {
    __shared__ int sh[256];
    const int t = threadIdx.x;
    const int idx = blockIdx.x * 256 + t;
    int v = (idx < N_NODES) ? cnt[idx] : 0;
    sh[t] = v;
    __syncthreads();
    for (int off = 1; off < 256; off <<= 1) {
        int x = (t >= off) ? sh[t - off] : 0;
        __syncthreads();
        sh[t] += x;
        __syncthreads();
    }
    if (idx < N_NODES) offs[idx] = sh[t] - v;
    if (t == 255) bsum[blockIdx.x] = sh[255];
}

// exclusive scan of block sums (single block, nb <= 256)
__global__ __launch_bounds__(256)
void scan_bsum(int* __restrict__ bsum, int nb) {
    __shared__ int sh[256];
    const int t = threadIdx.x;
    int v = (t < nb) ? bsum[t] : 0;
    sh[t] = v;
    __syncthreads();
    for (int off = 1; off < 256; off <<= 1) {
        int x = (t >= off) ? sh[t - off] : 0;
        __syncthreads();
        sh[t] += x;
        __syncthreads();
    }
    if (t < nb) bsum[t] = sh[t] - v;
}

// offs += base; cur = offs; offs[N] = n_edges
__global__ __launch_bounds__(256)
void add_base(int* __restrict__ offs, const int* __restrict__ bsum,
              int* __restrict__ cur, int n_edges) {
    const int idx = blockIdx.x * 256 + threadIdx.x;
    if (idx < N_NODES) {
        int o = offs[idx] + bsum[idx >> 8];
        offs[idx] = o;
        cur[idx] = o;
    }
    if (idx == 0) offs[N_NODES] = n_edges;
}

// bucket edge ids by destination
__global__ void fill_elist(const int* __restrict__ dst, int* __restrict__ cur,
                           int* __restrict__ elist, int n) {
    int i = blockIdx.x * blockDim.x + threadIdx.x;
    if (i < n) {
        int d = dst[i];
        int pos = atomicAdd(&cur[d], 1);
        elist[pos] = i;
    }
}

// Kernel 4: per-(node, col-half) relu-sum -> Mvb (bf16).
// E rows here are single-use across the whole kernel -> nontemporal loads
// (don't evict Mv/W/elist from L2/L3 with dead lines).
__global__ __launch_bounds__(256)
void node_gather_sum(const float* __restrict__ E,
                     const int* __restrict__ offs,
                     const int* __restrict__ elist,
                     unsigned int* __restrict__ Mvb) {
    const int w    = blockIdx.x * 4 + (threadIdx.x >> 6);
    const int node = w >> 1;
    const int half = w & 1;
    const int lane = threadIdx.x & 63;
    if (node >= N_NODES) return;
    const f32x2* Eh = (const f32x2*)(E + half * 128 + lane * 2);
    const int s0 = offs[node];
    const int s1 = offs[node + 1];
    float ax = 0.f, ay = 0.f;
    int j = s0;
    for (; j + 4 <= s1; j += 4) {
        const int e0 = elist[j], e1 = elist[j + 1], e2 = elist[j + 2], e3 = elist[j + 3];
        f32x2 v0 = __builtin_nontemporal_load(Eh + (size_t)e0 * (HIDDEN / 2));
        f32x2 v1 = __builtin_nontemporal_load(Eh + (size_t)e1 * (HIDDEN / 2));
        f32x2 v2 = __builtin_nontemporal_load(Eh + (size_t)e2 * (HIDDEN / 2));
        f32x2 v3 = __builtin_nontemporal_load(Eh + (size_t)e3 * (HIDDEN / 2));
        ax += fmaxf(v0.x, 0.f) + fmaxf(v1.x, 0.f) + fmaxf(v2.x, 0.f) + fmaxf(v3.x, 0.f);
        ay += fmaxf(v0.y, 0.f) + fmaxf(v1.y, 0.f) + fmaxf(v2.y, 0.f) + fmaxf(v3.y, 0.f);
    }
    for (; j < s1; ++j) {
        f32x2 v = __builtin_nontemporal_load(Eh + (size_t)elist[j] * (HIDDEN / 2));
        ax += fmaxf(v.x, 0.f);
        ay += fmaxf(v.y, 0.f);
    }
    Mvb[(size_t)node * 128 + half * 64 + lane] = f2bf(ax) | (f2bf(ay) << 16);
}

// Kernel 5: out = (Mv[src] - relu(E[rev])) @ W.T + b   (fused, LDS-staged)
// Wave-per-row staging (1KB coalesced E, 512B Mv); swapped MFMA operands ->
// float4 epilogue, NONTEMPORAL stores (out is write-once; keep L3 for E's
// rev-collision reuse).
__global__ __launch_bounds__(256, 3)
void gemm_fused(const float* __restrict__ E,
                const int* __restrict__ src,
                const int* __restrict__ rev,
                const unsigned int* __restrict__ Mvb,
                const ushort_t* __restrict__ Wf,
                const float* __restrict__ bias,
                float* __restrict__ out, int n_edges) {
    __shared__ __align__(16) unsigned char lds[BM * LDSROW];
    const int tid = threadIdx.x;
    const int row0 = blockIdx.x * BM;
    const int lane = tid & 63;
    const int wid  = tid >> 6;

    // ---- stage A tile: A[r][k] = Mv[src[r]][k] - relu(E[rev[r]][k]), bf16,
    // XOR-swizzled 16B slots: slot ^= (row & 7). 16 rows per wave.
    {
        const int wrow = wid * 16;
#pragma unroll
        for (int rr = 0; rr < 16; rr += 4) {
            float4 ev[4];
            uint2  mv[4];
            const int rbase = wrow + rr;
#pragma unroll
            for (int i = 0; i < 4; ++i) {
                int gr = row0 + rbase + i;
                int grc = (gr < n_edges) ? gr : (n_edges - 1);
                const int s  = src[grc];
                const int rv = rev[grc];
                ev[i] = *(const float4*)(E + (size_t)rv * HIDDEN + lane * 4);
                mv[i] = *(const uint2*)(Mvb + (size_t)s * (HIDDEN / 2) + lane * 2);
            }
#pragma unroll
            for (int i = 0; i < 4; ++i) {
                const int r = rbase + i;
                uint2 o;
                o.x = f2bf(bf2f(mv[i].x & 0xffffu) - fmaxf(ev[i].x, 0.f)) |
                      (f2bf(bf2f(mv[i].x >> 16)    - fmaxf(ev[i].y, 0.f)) << 16);
                o.y = f2bf(bf2f(mv[i].y & 0xffffu) - fmaxf(ev[i].z, 0.f)) |
                      (f2bf(bf2f(mv[i].y >> 16)    - fmaxf(ev[i].w, 0.f)) << 16);
                const int slot = (lane >> 1) ^ (r & 7);
                *(uint2*)(lds + r * LDSROW + slot * 16 + (lane & 1) * 8) = o;
            }
        }
    }
    __syncthreads();

    // ---- MFMA: each wave owns 64 rows x 64 cols
    const int l15   = lane & 15;
    const int hi16  = lane >> 4;
    const int wcol0 = wid * 64;
    const int r7l   = l15 & 7;

    f32x4 acc[4][4];
#pragma unroll
    for (int m = 0; m < 4; ++m)
#pragma unroll
        for (int n = 0; n < 4; ++n)
            acc[m][n] = (f32x4){0.f, 0.f, 0.f, 0.f};

#pragma unroll 2
    for (int kk = 0; kk < 8; ++kk) {
        const int slotbyte = ((kk * 4 + hi16) ^ r7l) * 16;
        short8 a[4], bfr[4];
#pragma unroll
        for (int m = 0; m < 4; ++m)
            a[m] = *(const short8*)(lds + (m * 16 + l15) * LDSROW + slotbyte);
#pragma unroll
        for (int n = 0; n < 4; ++n)
            bfr[n] = *(const short8*)(Wf + (size_t)((((wid * 4 + n) * 8 + kk) * 64 + lane) << 3));
#pragma unroll
        for (int m = 0; m < 4; ++m)
#pragma unroll
            for (int n = 0; n < 4; ++n)
                acc[m][n] = __builtin_amdgcn_mfma_f32_16x16x32_bf16(bfr[n], a[m], acc[m][n], 0, 0, 0);
    }

    // ---- epilogue: lane holds edge row (l15) x 4 consecutive out cols;
    // nontemporal f32x4 stores.
#pragma unroll
    for (int m = 0; m < 4; ++m) {
        const int row = row0 + m * 16 + l15;
        if (row < n_edges) {
            float* orow = out + (size_t)row * HIDDEN;
#pragma unroll
            for (int n = 0; n < 4; ++n) {
                const int cb = wcol0 + n * 16 + hi16 * 4;
                float4 bv = *(const float4*)(bias + cb);
                f32x4 o;
                o.x = acc[m][n][0] + bv.x;
                o.y = acc[m][n][1] + bv.y;
                o.z = acc[m][n][2] + bv.z;
                o.w = acc[m][n][3] + bv.w;
                __builtin_nontemporal_store(o, (f32x4*)(orow + cb));
            }
        }
    }
}

extern "C" void kernel_launch(void* const* d_in, const int* in_sizes, int n_in,
                              void* d_out, int out_size, void* d_ws, size_t ws_size,
                              hipStream_t stream) {
    const float* E    = (const float*)d_in[0];
    const int*   ei   = (const int*)d_in[1];
    const int*   rev  = (const int*)d_in[2];
    const float* W    = (const float*)d_in[3];
    const float* bias = (const float*)d_in[4];
    float* out = (float*)d_out;
    const int n_edges = in_sizes[2];
    const int* srcI = ei;              // edge_index[0]
    const int* dstI = ei + n_edges;    // edge_index[1]

    char* ws = (char*)d_ws;
    unsigned int* Mvb  = (unsigned int*)(ws + OFF_MVB);
    ushort_t*     Wf   = (ushort_t*)(ws + OFF_WF);
    int*          cnt  = (int*)(ws + OFF_CNT);
    int*          offs = (int*)(ws + OFF_OFFS);
    int*          cur  = (int*)(ws + OFF_CUR);
    int*          elst = (int*)(ws + OFF_ELIST);
    int*          bsum = (int*)(ws + OFF_BSUM);

    zero_i32<<<SCAN_NBLK, 256, 0, stream>>>(cnt, N_NODES);
    convert_w_frag<<<(HIDDEN * HIDDEN + 255) / 256, 256, 0, stream>>>(W, Wf, HIDDEN * HIDDEN);

    count_dst<<<(n_edges + 255) / 256, 256, 0, stream>>>(dstI, cnt, n_edges);
    block_scan<<<SCAN_NBLK, 256, 0, stream>>>(cnt, offs, bsum);
    scan_bsum<<<1, 256, 0, stream>>>(bsum, SCAN_NBLK);
    add_base<<<SCAN_NBLK, 256, 0, stream>>>(offs, bsum, cur, n_edges);
    fill_elist<<<(n_edges + 255) / 256, 256, 0, stream>>>(dstI, cur, elst, n_edges);

    const int nwaves = N_NODES * 2;
    node_gather_sum<<<(nwaves + 3) / 4, 256, 0, stream>>>(E, offs, elst, Mvb);

    const int nblk = (n_edges + BM - 1) / BM;
    gemm_fused<<<nblk, 256, 0, stream>>>(E, srcI, rev, Mvb, Wf, bias, out, n_edges);
}